// Round 10
// baseline (197.954 us; speedup 1.0000x reference)
//
#include <hip/hip_runtime.h>
#include <math.h>

#define VOCAB 2048
#define TPB   256
#define RPB   4            // rows (waves) per block
#define NBINS 64
// 64 bins cover (m - v) in [0, 64/6 = 10.667); kept tokens provably have
// m - v <= ln(2048/0.05) = 10.62, so the top-p crossing is always inside.
#define BIN_SCALE 6.0f
#define CAP   512          // compaction capacity per row (boundary & kept)

typedef float vf4 __attribute__((ext_vector_type(4)));

// One wave (64 lanes) per row, 32 elements per lane, ZERO block barriers.
// All reductions are in-wave shfl butterflies; LDS segments are wave-private.
// KEY CHANGES vs R1:
//  (a) keep decision via VALUE THRESHOLD: kept-ness is monotone in value, so
//      the boundary bin resolves to vcut = min kept candidate value. One
//      per-candidate pass (~bcnt broadcast LDS reads per ROW) replaces R1's
//      per-j-slot dynamic LDS loops (~300 serial reads per LANE) — the
//      dominant latency chain. The elem sweep is then register-only.
//  (b) e[] not stored; __expf recomputed on demand (R4-validated numerics).
//      Register state halves -> launch_bounds(256,5) caps VGPR at 51 so
//      5 waves/SIMD can be resident (R1's 64-VGPR build ran at 4/SIMD).
__global__ __launch_bounds__(TPB, 5) void sampler_kernel(
    const float* __restrict__ logits,
    const float* __restrict__ uni,
    float* __restrict__ out_idx,    // [B]   sampled index as float
    float* __restrict__ out_probs)  // [B,V] filtered softmax
{
    const int lane = threadIdx.x & 63;
    const int wid  = threadIdx.x >> 6;
    const int row  = (blockIdx.x << 2) | wid;

    __shared__ float s_bins[RPB][NBINS];
    __shared__ float s_cv[RPB][CAP];   // phase A: boundary values; phase B: kept values
    __shared__ float s_ci[RPB][CAP];   // phase A: boundary exps;   phase B: kept idx (bits)
    __shared__ int   s_bcnt[RPB];
    __shared__ int   s_kcnt[RPB];

    const float* lrow = logits    + (size_t)row * VOCAB;
    const float* urow = uni       + (size_t)row * VOCAB;
    float*       prow = out_probs + (size_t)row * VOCAB;

    // wave-private LDS init (1 bin per lane)
    s_bins[wid][lane] = 0.0f;
    if (lane == 0) { s_bcnt[wid] = 0; s_kcnt[wid] = 0; }

    // ---- load + temperature scale (x*1.25f ~ x/0.8f to ~1 ulp) ----
    float s[32];
    #pragma unroll
    for (int j = 0; j < 8; j++) {
        vf4 a = *(const vf4*)(lrow + j * 256 + 4 * lane);
        s[4*j+0] = a.x * 1.25f;
        s[4*j+1] = a.y * 1.25f;
        s[4*j+2] = a.z * 1.25f;
        s[4*j+3] = a.w * 1.25f;
    }

    // ---- wave max (butterfly -> all lanes) ----
    float m0 = s[0], m1 = s[1], m2 = s[2], m3 = s[3];
    #pragma unroll
    for (int j = 4; j < 32; j += 4) {
        m0 = fmaxf(m0, s[j+0]); m1 = fmaxf(m1, s[j+1]);
        m2 = fmaxf(m2, s[j+2]); m3 = fmaxf(m3, s[j+3]);
    }
    float m = fmaxf(fmaxf(m0, m1), fmaxf(m2, m3));
    #pragma unroll
    for (int off = 32; off; off >>= 1)
        m = fmaxf(m, __shfl_xor(m, off));

    // ---- exp (recomputed, not stored), total sum, exp-mass histogram ----
    double p0 = 0.0, p1 = 0.0;
    #pragma unroll
    for (int j = 0; j < 32; j++) {
        float e = __expf(s[j] - m);
        if (j & 1) p1 += (double)e; else p0 += (double)e;
        int b = (int)((m - s[j]) * BIN_SCALE);
        if (b < NBINS) atomicAdd(&s_bins[wid][b], e);
    }
    double dp = p0 + p1;
    #pragma unroll
    for (int off = 32; off; off >>= 1)
        dp += __shfl_xor(dp, off);
    const double pS = 0.95 * dp;

    // ---- in-wave prefix scan of the 64 bins (1 bin per lane), find boundary ----
    const float bf = s_bins[wid][lane];      // same-wave DS order: atomics done
    double c = (double)bf;
    #pragma unroll
    for (int d = 1; d < 64; d <<= 1) {
        double o = __shfl_up(c, d);
        if (lane >= d) c += o;
    }
    const unsigned long long ball = __ballot(c > pS);
    const int bstar = ball ? (__ffsll(ball) - 1) : (NBINS - 1);
    double excl = c - (double)bf;            // exclusive prefix
    const double cumBefore = __shfl(excl, bstar);

    // ---- compact boundary-bin candidates (value, exp) to wave LDS ----
    #pragma unroll
    for (int j = 0; j < 32; j++) {
        int b = (int)((m - s[j]) * BIN_SCALE);
        if (b == bstar) {
            int pos = atomicAdd(&s_bcnt[wid], 1);
            if (pos < CAP) {
                s_cv[wid][pos] = s[j];
                s_ci[wid][pos] = __expf(s[j] - m);
            }
        }
    }
    const int bcnt = min(s_bcnt[wid], CAP);

    // ---- tie-resolve: per-candidate kept flag -> value cutoff vcut ----
    // kept(v) <=> cumBefore + sum_{cv > v} ci <= pS  (monotone in v), so
    // the boundary set is exactly { v : v >= vcut }, vcut = min kept value.
    float vcut = INFINITY;
    float bk   = 0.0f;                       // kept boundary exp-mass
    for (int i = lane; i < bcnt; i += 64) {
        float vi = s_cv[wid][i];
        float part = 0.0f;
        for (int t = 0; t < bcnt; t++)       // broadcast reads, conflict-free
            if (s_cv[wid][t] > vi) part += s_ci[wid][t];
        if (cumBefore + (double)part <= pS) {
            vcut = fminf(vcut, vi);
            bk  += s_ci[wid][i];
        }
    }
    #pragma unroll
    for (int off = 32; off; off >>= 1) {
        vcut = fminf(vcut, __shfl_xor(vcut, off));
        bk  += __shfl_xor(bk, off);
    }
    const float invSK = 1.0f / (float)(cumBefore + (double)bk);

    // ---- elem sweep: register-only keep decision + probs write ----
    unsigned keptMask = 0;
    #pragma unroll
    for (int j = 0; j < 32; j++) {
        int b = (int)((m - s[j]) * BIN_SCALE);
        bool kept = (b < bstar) || (b == bstar && s[j] >= vcut);
        if (kept) keptMask |= (1u << j);
    }
    #pragma unroll
    for (int j = 0; j < 8; j++) {
        vf4 p;
        p.x = ((keptMask >> (4*j+0)) & 1u) ? __expf(s[4*j+0] - m) * invSK : 0.0f;
        p.y = ((keptMask >> (4*j+1)) & 1u) ? __expf(s[4*j+1] - m) * invSK : 0.0f;
        p.z = ((keptMask >> (4*j+2)) & 1u) ? __expf(s[4*j+2] - m) * invSK : 0.0f;
        p.w = ((keptMask >> (4*j+3)) & 1u) ? __expf(s[4*j+3] - m) * invSK : 0.0f;
        __builtin_nontemporal_store(p, (vf4*)(prow + j * 256 + 4 * lane));
    }

    // ---- compact KEPT tokens (value, idx); exact in-register fallback on overflow ----
    unsigned ovf = 0;
    #pragma unroll
    for (int j = 0; j < 32; j++) {
        if ((keptMask >> j) & 1u) {
            int pos = atomicAdd(&s_kcnt[wid], 1);
            if (pos < CAP) {
                s_cv[wid][pos] = s[j];
                s_ci[wid][pos] = __int_as_float((j >> 2) * 256 + 4 * lane + (j & 3));
            } else {
                ovf |= (1u << j);
            }
        }
    }
    const int kc = min(s_kcnt[wid], CAP);

    // ---- Gumbel-max over kept tokens (precise logf, sparse u gather) ----
    unsigned long long key = 0ull;   // any real z maps above 0
    for (int i = lane; i < kc; i += 64) {
        float sv  = s_cv[wid][i];
        int   idx = __float_as_int(s_ci[wid][i]);
        float uv  = urow[idx];
        float g   = -logf(-logf(uv));
        float z   = sv + g;
        unsigned zb = __float_as_uint(z);
        zb = (zb & 0x80000000u) ? ~zb : (zb | 0x80000000u);  // order-preserving map
        unsigned long long kk =
            ((unsigned long long)zb << 32) | (unsigned)(VOCAB - 1 - idx); // min-idx tiebreak
        key = (kk > key) ? kk : key;
    }
    if (ovf != 0) {                           // cold exact path: row had >CAP kept
        #pragma unroll
        for (int j = 0; j < 32; j++) {
            if ((ovf >> j) & 1u) {
                int   idx = (j >> 2) * 256 + 4 * lane + (j & 3);
                float uv  = urow[idx];
                float g   = -logf(-logf(uv));
                float z   = s[j] + g;
                unsigned zb = __float_as_uint(z);
                zb = (zb & 0x80000000u) ? ~zb : (zb | 0x80000000u);
                unsigned long long kk =
                    ((unsigned long long)zb << 32) | (unsigned)(VOCAB - 1 - idx);
                key = (kk > key) ? kk : key;
            }
        }
    }
    #pragma unroll
    for (int off = 32; off; off >>= 1) {
        unsigned long long ok = __shfl_xor(key, off);
        key = (ok > key) ? ok : key;
    }
    if (lane == 0)
        out_idx[row] = (float)(VOCAB - 1 - (int)(key & 0xFFFFFFFFu));
}

extern "C" void kernel_launch(void* const* d_in, const int* in_sizes, int n_in,
                              void* d_out, int out_size, void* d_ws, size_t ws_size,
                              hipStream_t stream) {
    const float* logits = (const float*)d_in[0];
    const float* u      = (const float*)d_in[1];
    const int B = in_sizes[0] / VOCAB;   // 8192
    float* out_idx   = (float*)d_out;          // sampled [B,1] flattened
    float* out_probs = (float*)d_out + B;      // probs [B,V]
    sampler_kernel<<<B / RPB, TPB, 0, stream>>>(logits, u, out_idx, out_probs);
}